// Round 1
// 644.113 us; speedup vs baseline: 1.1040x; 1.1040x over previous
//
#include <hip/hip_runtime.h>

// AttFusion R3: register-resident, single-read, balanced-grid design.
//
// R2 post-mortem: 711us at ~0.8 TB/s effective -> latency-bound, not BW-bound.
// Root cause: grid of 864 blocks (3.4/CU, no backfill) + per-batch imbalance
// (len 5,3,6,2) left the len-6 batch's 216 blocks at ~1 wave/SIMD for most of
// the kernel.
//
// R3 changes:
//  * tile = 8 float4-pixels x all 256 ch (32 groups of 8 ch/thread)
//    -> 864 tiles/batch x 4 batches = 3456 blocks, interleaved (b = bid % B)
//    -> ~7 rounds of backfill, mixed-length tail.
//  * each thread keeps its LEN x 8 float4 x-tile in REGISTERS between the
//    score pass and the weighted-sum pass: x read exactly once, pass 2 has
//    zero global loads, all 48 pass-1 loads independent (deep MLP).
//  * __launch_bounds__(256,2): cap VGPR at 256 (avoid 1-wave/SIMD cliff).

#define CC 256
#define PP (96 * 288)      // 27648 pixels
#define P4 (PP / 4)        // 6912 float4 per (record,channel) row
#define LMAXC 6
#define TPX 8              // float4-pixels per block tile
#define NGRP 32            // channel groups (8 channels each)

template <int LEN>
__device__ __forceinline__ void att_body(
    const float4* __restrict__ xbase,   // x + off*CP4 + c0*P4 + tile*TPX + pxl
    float4* __restrict__ obase,         // out + b*CP4 + c0*P4 + tile*TPX + pxl
    float4 (&red)[LMAXC][NGRP][TPX],
    float4 (&sc)[LMAXC][TPX],
    float4 (&att)[LMAXC][TPX],
    int pxl, int grp, int tid)
{
    const size_t CP4 = (size_t)CC * P4;

    // ---- Pass 1: load LEN x 8 float4 into registers (x read once) ----
    float4 xd[LEN][8];
#pragma unroll
    for (int ci = 0; ci < 8; ++ci) {
#pragma unroll
        for (int l = 0; l < LEN; ++l)
            xd[l][ci] = xbase[(size_t)l * CP4 + (size_t)ci * P4];
    }

    // partial scores over this thread's 8 channels (l=0 gives q.q)
    float4 s[LEN];
#pragma unroll
    for (int l = 0; l < LEN; ++l) s[l] = make_float4(0.f, 0.f, 0.f, 0.f);
#pragma unroll
    for (int ci = 0; ci < 8; ++ci) {
        const float4 x0 = xd[0][ci];
#pragma unroll
        for (int l = 0; l < LEN; ++l) {
            const float4 xl = xd[l][ci];
            s[l].x = fmaf(x0.x, xl.x, s[l].x);
            s[l].y = fmaf(x0.y, xl.y, s[l].y);
            s[l].z = fmaf(x0.z, xl.z, s[l].z);
            s[l].w = fmaf(x0.w, xl.w, s[l].w);
        }
    }

#pragma unroll
    for (int l = 0; l < LEN; ++l) red[l][grp][pxl] = s[l];
    __syncthreads();

    // ---- Reduce over the 32 channel groups: one thread per (l, px) ----
    if (tid < 8 * LEN) {
        const int l = tid >> 3, px = tid & 7;
        float4 a = make_float4(0.f, 0.f, 0.f, 0.f);
#pragma unroll
        for (int g = 0; g < NGRP; ++g) {
            const float4 r = red[l][g][px];
            a.x += r.x; a.y += r.y; a.z += r.z; a.w += r.w;
        }
        // scale = 1/sqrt(256)
        sc[l][px] = make_float4(a.x * 0.0625f, a.y * 0.0625f,
                                a.z * 0.0625f, a.w * 0.0625f);
    }
    __syncthreads();

    // ---- Softmax over l: one thread per px4 ----
    if (tid < TPX) {
        float4 v[LEN];
#pragma unroll
        for (int l = 0; l < LEN; ++l) v[l] = sc[l][tid];
        float4 m = v[0];
#pragma unroll
        for (int l = 1; l < LEN; ++l) {
            m.x = fmaxf(m.x, v[l].x); m.y = fmaxf(m.y, v[l].y);
            m.z = fmaxf(m.z, v[l].z); m.w = fmaxf(m.w, v[l].w);
        }
        float4 sum = make_float4(0.f, 0.f, 0.f, 0.f);
#pragma unroll
        for (int l = 0; l < LEN; ++l) {
            v[l].x = __expf(v[l].x - m.x); sum.x += v[l].x;
            v[l].y = __expf(v[l].y - m.y); sum.y += v[l].y;
            v[l].z = __expf(v[l].z - m.z); sum.z += v[l].z;
            v[l].w = __expf(v[l].w - m.w); sum.w += v[l].w;
        }
        const float4 inv = make_float4(1.f / sum.x, 1.f / sum.y,
                                       1.f / sum.z, 1.f / sum.w);
#pragma unroll
        for (int l = 0; l < LEN; ++l)
            att[l][tid] = make_float4(v[l].x * inv.x, v[l].y * inv.y,
                                      v[l].z * inv.z, v[l].w * inv.w);
    }
    __syncthreads();

    // ---- Pass 2: weighted sum straight from registers, zero reloads ----
    float4 a[LEN];
#pragma unroll
    for (int l = 0; l < LEN; ++l) a[l] = att[l][pxl];

#pragma unroll
    for (int ci = 0; ci < 8; ++ci) {
        float4 acc;
        acc.x = a[0].x * xd[0][ci].x;
        acc.y = a[0].y * xd[0][ci].y;
        acc.z = a[0].z * xd[0][ci].z;
        acc.w = a[0].w * xd[0][ci].w;
#pragma unroll
        for (int l = 1; l < LEN; ++l) {
            acc.x = fmaf(a[l].x, xd[l][ci].x, acc.x);
            acc.y = fmaf(a[l].y, xd[l][ci].y, acc.y);
            acc.z = fmaf(a[l].z, xd[l][ci].z, acc.z);
            acc.w = fmaf(a[l].w, xd[l][ci].w, acc.w);
        }
        obase[(size_t)ci * P4] = acc;
    }
}

__global__ __launch_bounds__(256, 2) void attfusion_kernel(
    const float4* __restrict__ x, const int* __restrict__ rl,
    float4* __restrict__ out, int B)
{
    __shared__ float4 red[LMAXC][NGRP][TPX];
    __shared__ float4 sc[LMAXC][TPX];
    __shared__ float4 att[LMAXC][TPX];

    const int tid = threadIdx.x;
    const int pxl = tid & 7;          // float4-pixel within tile
    const int grp = tid >> 3;         // channel group 0..31 (8 ch each)

    const unsigned bid  = blockIdx.x;
    const int b    = bid % (unsigned)B;       // interleave batches in dispatch order
    const int tile = bid / (unsigned)B;

    int off = 0;
    for (int i = 0; i < b; ++i) off += rl[i];
    int len = rl[b];
    if (len > LMAXC) len = LMAXC;
    if (len < 1)     len = 1;

    const size_t CP4 = (size_t)CC * P4;
    const int c0 = grp * 8;
    const float4* xbase = x   + (size_t)off * CP4 + (size_t)c0 * P4
                              + (size_t)tile * TPX + pxl;
    float4*       obase = out + (size_t)b   * CP4 + (size_t)c0 * P4
                              + (size_t)tile * TPX + pxl;

    switch (len) {
        case 1: att_body<1>(xbase, obase, red, sc, att, pxl, grp, tid); break;
        case 2: att_body<2>(xbase, obase, red, sc, att, pxl, grp, tid); break;
        case 3: att_body<3>(xbase, obase, red, sc, att, pxl, grp, tid); break;
        case 4: att_body<4>(xbase, obase, red, sc, att, pxl, grp, tid); break;
        case 5: att_body<5>(xbase, obase, red, sc, att, pxl, grp, tid); break;
        default: att_body<6>(xbase, obase, red, sc, att, pxl, grp, tid); break;
    }
}

extern "C" void kernel_launch(void* const* d_in, const int* in_sizes, int n_in,
                              void* d_out, int out_size, void* d_ws, size_t ws_size,
                              hipStream_t stream) {
    const float4* x   = (const float4*)d_in[0];
    const int*    rl  = (const int*)d_in[1];
    float4*       out = (float4*)d_out;
    const int B = in_sizes[1];                 // 4
    dim3 grid((P4 / TPX) * B);                 // 864 tiles x 4 batches = 3456
    attfusion_kernel<<<grid, 256, 0, stream>>>(x, rl, out, B);
}